// Round 12
// baseline (166.974 us; speedup 1.0000x reference)
//
#include <hip/hip_runtime.h>
#include <stdint.h>

// ---------------------------------------------------------------------------
// ProteinFeaturesNA on MI355X — R12: R11's MX-scaled fp8 K=128 kernel with
// occupancy push: KSPLIT=8, 4-wave/128-row blocks (grid 120x8), B-stream
// shared by 4 waves/block. Outputs (f32): V, E, E_idx.
// Dispatches: kPrep, kC, kD.
// ---------------------------------------------------------------------------

#define NRES   512
#define TOPK   30
#define NATOM  26
#define KTOT   10832
#define NBLK128 85            // 128-k blocks (padded K = 10880)
#define MTOT   (NRES*TOPK)    // 15360
#define NOUT   128
#define KSPLIT 8

#define OFF_AUGX4  0u          // 512*26 float4        = 212992
#define OFF_EIDX   212992u     // 512*30 i32           =  61440 -> 274432
#define OFF_WSWZ   274432u     // 85*8 frag * 2048 B   = 1392640 -> 1667072
#define OFF_EPART  1667072u    // 8*15360*128 bf16     = 31457280 -> 33124352

#define OUT_V     0
#define OUT_E     (NRES*NOUT)            // 65536
#define OUT_EIDX  (OUT_E + MTOT*NOUT)    // 2031616

typedef __attribute__((ext_vector_type(4))) float f32x4;
typedef __attribute__((ext_vector_type(8))) int   i32x8;

#define SA_C    0.96089792702915984f     // sqrt(log2 e)/1.25
#define MU0_C   1.9217958540583197f      // 2*SA
#define MUS_C   1.2811972360388798f      // (4/3)*SA
#define MUS2_C  (MUS_C*MUS_C)
#define MU3_C   (MU0_C + 3.0f*MUS_C)
#define MU11_C  (MU0_C + 11.0f*MUS_C)
#define SCL1    0x7f7f7f7f               // e8m0 unity scales

__device__ __forceinline__ unsigned short f2bf(float f) {
    unsigned u = __builtin_bit_cast(unsigned, f);
    return (unsigned short)((u + 0x7fffu + ((u >> 16) & 1u)) >> 16);
}
__device__ __forceinline__ float bf2f(unsigned short u) {
    return __builtin_bit_cast(float, (unsigned)u << 16);
}
__device__ __forceinline__ float bflo(unsigned u) {
    return __builtin_bit_cast(float, u << 16);
}
__device__ __forceinline__ float bfhi(unsigned u) {
    return __builtin_bit_cast(float, u & 0xffff0000u);
}
__device__ __forceinline__ unsigned long long shfl_xor_u64(unsigned long long v, int m) {
    unsigned lo = (unsigned)v, hi = (unsigned)(v >> 32);
    lo = (unsigned)__shfl_xor((int)lo, m, 64);
    hi = (unsigned)__shfl_xor((int)hi, m, 64);
    return ((unsigned long long)hi << 32) | lo;
}
__device__ __forceinline__ float fexp2(float x) { return __builtin_amdgcn_exp2f(x); }
__device__ __forceinline__ float fsqrtf(float x) { return __builtin_amdgcn_sqrtf(x); }

// 16 RBF features of one slot: one distance, two 8-feature center-chains.
// (Single 16-chain is numerically impossible: e3 underflows fp32 at Ds~24
// while e15 is still fp8-nonzero.)
__device__ __forceinline__ uint4 gen16(float4 xi, float jx, float jy, float jz,
                                       float CC) {
    float dx = xi.x - jx, dy = xi.y - jy, dz = xi.z - jz;
    float d2 = __builtin_fmaf(dx, dx, __builtin_fmaf(dy, dy,
               __builtin_fmaf(dz, dz, 1e-6f)));
    float Ds = fsqrtf(d2) * SA_C;
    Ds = fminf(Ds, 45.0f);
    Ds = (xi.w == 0.0f) ? 45.0f : Ds;             // i-masked -> all features 0
    uint4 o;
    {   // feats 0..7, center f3
        float u = Ds - MU3_C;
        float e3 = fexp2(-(u * u));
        float r  = fexp2(__builtin_fmaf( 2.0f*MUS_C, u, -MUS2_C));
        float sd = fexp2(__builtin_fmaf(-2.0f*MUS_C, u, -MUS2_C));
        float e4=e3*r;  r*=CC;  float e5=e4*r;  r*=CC;  float e6=e5*r;  r*=CC;  float e7=e6*r;
        float e2=e3*sd; sd*=CC; float e1=e2*sd; sd*=CC; float e0=e1*sd;
        int p = __builtin_amdgcn_cvt_pk_fp8_f32(e0, e1, 0, false);
        p     = __builtin_amdgcn_cvt_pk_fp8_f32(e2, e3, p, true);
        int q = __builtin_amdgcn_cvt_pk_fp8_f32(e4, e5, 0, false);
        q     = __builtin_amdgcn_cvt_pk_fp8_f32(e6, e7, q, true);
        o.x = (unsigned)p; o.y = (unsigned)q;
    }
    {   // feats 8..15, center f11
        float u = Ds - MU11_C;
        float e3 = fexp2(-(u * u));
        float r  = fexp2(__builtin_fmaf( 2.0f*MUS_C, u, -MUS2_C));
        float sd = fexp2(__builtin_fmaf(-2.0f*MUS_C, u, -MUS2_C));
        float e4=e3*r;  r*=CC;  float e5=e4*r;  r*=CC;  float e6=e5*r;  r*=CC;  float e7=e6*r;
        float e2=e3*sd; sd*=CC; float e1=e2*sd; sd*=CC; float e0=e1*sd;
        int p = __builtin_amdgcn_cvt_pk_fp8_f32(e0, e1, 0, false);
        p     = __builtin_amdgcn_cvt_pk_fp8_f32(e2, e3, p, true);
        int q = __builtin_amdgcn_cvt_pk_fp8_f32(e4, e5, 0, false);
        q     = __builtin_amdgcn_cvt_pk_fp8_f32(e6, e7, q, true);
        o.z = (unsigned)p; o.w = (unsigned)q;
    }
    return o;
}

// -------------------------------------------------------------- kernel Prep --
// blocks [0,512): aug atoms + V-LN + top-30; blocks [512,896): W swizzle.
// W fragment (K=128 layout): frag (d, nt) = 64 lanes x 32 B; lane
// (qd*16 + (n&15)) bytes cc*16+f = fp8 W[n][slot 8d+2qd+cc, feature f].
__global__ __launch_bounds__(256) void kPrep(
    const float* __restrict__ X, const float* __restrict__ Xm,
    const float* __restrict__ prot, const float* __restrict__ dna,
    const float* __restrict__ rna, const int* __restrict__ ptype,
    const float* __restrict__ Wn, const float* __restrict__ gn,
    const float* __restrict__ bn, const float* __restrict__ We,
    char* __restrict__ ws, float* __restrict__ out)
{
    if (blockIdx.x >= NRES) {
        int idx = blockIdx.x - NRES;
        int n = idx / 3;
        int s = (idx - n*3)*256 + threadIdx.x;
        if (s >= 677) return;
        const float* src = We + (size_t)n*KTOT + ((s < 676) ? (16 + s*16) : 0);
        float4 v0 = ((const float4*)src)[0];
        float4 v1 = ((const float4*)src)[1];
        float4 v2 = ((const float4*)src)[2];
        float4 v3 = ((const float4*)src)[3];
        int d = s >> 3, sl = s & 7, qd2 = sl >> 1, cc = sl & 1;
        size_t base = OFF_WSWZ
                    + (((size_t)(d*8 + (n >> 4))*64) + (size_t)(qd2*16 + (n & 15)))*32
                    + (size_t)cc*16;
        int r0 = __builtin_amdgcn_cvt_pk_fp8_f32(v0.x, v0.y, 0, false);
        r0     = __builtin_amdgcn_cvt_pk_fp8_f32(v0.z, v0.w, r0, true);
        int r1 = __builtin_amdgcn_cvt_pk_fp8_f32(v1.x, v1.y, 0, false);
        r1     = __builtin_amdgcn_cvt_pk_fp8_f32(v1.z, v1.w, r1, true);
        int r2 = __builtin_amdgcn_cvt_pk_fp8_f32(v2.x, v2.y, 0, false);
        r2     = __builtin_amdgcn_cvt_pk_fp8_f32(v2.z, v2.w, r2, true);
        int r3 = __builtin_amdgcn_cvt_pk_fp8_f32(v3.x, v3.y, 0, false);
        r3     = __builtin_amdgcn_cvt_pk_fp8_f32(v3.z, v3.w, r3, true);
        *(uint4*)(ws + base) = make_uint4((unsigned)r0, (unsigned)r1,
                                          (unsigned)r2, (unsigned)r3);
        return;
    }

    const int i = blockIdx.x, t = threadIdx.x;
    if (t >= 128) return;
    float4* augX4 = (float4*)(ws + OFF_AUGX4);
    int*    Eidx  = (int*)(ws + OFF_EIDX);
    const float* Xi = X + i * 72;

    if (t < 26) {
        float x, y, z, mk;
        if (t < 24) {
            x = Xi[t*3]; y = Xi[t*3+1]; z = Xi[t*3+2];
            mk = Xm[i*24 + t];
        } else if (t == 24) {
            float b0 = Xi[3]-Xi[0], b1 = Xi[4]-Xi[1], b2 = Xi[5]-Xi[2];
            float c0 = Xi[6]-Xi[3], c1 = Xi[7]-Xi[4], c2 = Xi[8]-Xi[5];
            float a0 = b1*c2-b2*c1, a1 = b2*c0-b0*c2, a2 = b0*c1-b1*c0;
            x = -0.58273431f*a0 + 0.56802827f*b0 - 0.54067466f*c0 + Xi[3];
            y = -0.58273431f*a1 + 0.56802827f*b1 - 0.54067466f*c1 + Xi[4];
            z = -0.58273431f*a2 + 0.56802827f*b2 - 0.54067466f*c2 + Xi[5];
            mk = prot[i];
        } else {
            const float* O4 = Xi + 33; const float* C1 = Xi + 45; const float* C2 = Xi + 42;
            float b0 = C1[0]-O4[0], b1 = C1[1]-O4[1], b2 = C1[2]-O4[2];
            float c0 = C2[0]-C1[0], c1 = C2[1]-C1[1], c2 = C2[2]-C1[2];
            float a0 = b1*c2-b2*c1, a1 = b2*c0-b0*c2, a2 = b0*c1-b1*c0;
            x = -0.56967352f*a0 + 0.51055973f*b0 - 0.53122153f*c0 + C1[0];
            y = -0.56967352f*a1 + 0.51055973f*b1 - 0.53122153f*c1 + C1[1];
            z = -0.56967352f*a2 + 0.51055973f*b2 - 0.53122153f*c2 + C1[2];
            mk = dna[i] + rna[i];
        }
        augX4[i*26 + t] = make_float4(x, y, z, mk);
    }

    // V layernorm (128 threads)
    __shared__ float red[4];
    int ty = ptype[i];
    float v = Wn[t*3 + ty];
    float s = v;
    #pragma unroll
    for (int off = 32; off; off >>= 1) s += __shfl_xor(s, off, 64);
    if ((t & 63) == 0) red[t>>6] = s;
    __syncthreads();
    float mean = (red[0] + red[1]) * (1.0f/128.0f);
    float d = v - mean;
    float s2 = d*d;
    #pragma unroll
    for (int off = 32; off; off >>= 1) s2 += __shfl_xor(s2, off, 64);
    if ((t & 63) == 0) red[2 + (t>>6)] = s2;
    __syncthreads();
    float var = (red[2] + red[3]) * (1.0f/128.0f);
    out[OUT_V + i*NOUT + t] = d * rsqrtf(var + 1e-5f) * gn[t] + bn[t];

    // top-30 (wave 0 only); Xc computed inline (bit-identical ops)
    if (t >= 64) return;
    const int l = t;
    float xi0 = Xi[3] + Xi[45], xi1 = Xi[4] + Xi[46], xi2 = Xi[5] + Xi[47];
    unsigned long long cand[8];
    #pragma unroll
    for (int sg = 0; sg < 8; sg++) {
        int j = sg*64 + l;
        const float* Xj = X + j*72;
        float c0 = Xj[3] + Xj[45], c1 = Xj[4] + Xj[46], c2 = Xj[5] + Xj[47];
        float dx = xi0 - c0, dy = xi1 - c1, dz = xi2 - c2;
        float dd = __fadd_rn(__fadd_rn(__fadd_rn(__fmul_rn(dx,dx), __fmul_rn(dy,dy)),
                                       __fmul_rn(dz,dz)), 1e-6f);
        float D = sqrtf(dd);
        cand[sg] = ((unsigned long long)__builtin_bit_cast(unsigned, D) << 32) | (unsigned)j;
    }
    for (int m = 0; m < TOPK; m++) {
        unsigned long long k = cand[0];
        #pragma unroll
        for (int sg = 1; sg < 8; sg++) if (cand[sg] < k) k = cand[sg];
        #pragma unroll
        for (int off = 32; off; off >>= 1) {
            unsigned long long o = shfl_xor_u64(k, off);
            if (o < k) k = o;
        }
        if (l == 0) {
            int j = (int)(k & 0xffffffffu);
            Eidx[i*TOPK + m] = j;
            out[OUT_EIDX + i*TOPK + m] = (float)j;
        }
        #pragma unroll
        for (int sg = 0; sg < 8; sg++) if (cand[sg] == k) cand[sg] = ~0ull;
    }
}

// ---------------------------------------------------------------- kernel C --
// grid (120, 8): block = 4 waves x 128 rows, K-eighth q. Wave w: row tiles
// r0 = bx*128 + w*32 + mlane, r1 = r0+16, all 128 cols. Lane (mlane, qd)
// covers k = qd*32..+31 = slots 8d+2qd, +1 per 128-k block d.
__global__ __launch_bounds__(256, 3) void kC(const int* __restrict__ Ridx,
                                             const int* __restrict__ chain,
                                             const float* __restrict__ Wp,
                                             const float* __restrict__ bp,
                                             char* __restrict__ ws)
{
    const int bx = blockIdx.x, q = blockIdx.y;
    const int t = threadIdx.x, lane = t & 63, w = t >> 6;
    const int mlane = lane & 15, qd = lane >> 4;

    const float4* augX4 = (const float4*)(ws + OFF_AUGX4);
    const int*    Eidx  = (const int*)(ws + OFF_EIDX);
    unsigned short* Ep  = (unsigned short*)(ws + OFF_EPART)
                        + (size_t)q * MTOT * NOUT;

    __shared__ uint2  jT[NATOM * 129];    // 26832 B, stride-129 padded
    __shared__ float4 iT[6 * 26];         //  2496 B
    __shared__ int    JrowS[128];

    if (t < 128) JrowS[t] = Eidx[bx*128 + t];
    __syncthreads();
    const int i_base = (bx*128) / TOPK;
    if (t < 6*26) {
        int il = t / 26, aa = t - il*26;
        int gi = i_base + il; gi = gi > 511 ? 511 : gi;
        iT[t] = augX4[(size_t)gi*26 + aa];
    }
    for (int wk = t; wk < NATOM*128; wk += 256) {
        int aa = wk >> 7, rl = wk & 127;
        float4 p = augX4[(size_t)JrowS[rl]*26 + aa];
        float x = p.x, y = p.y, z = p.z;
        if (p.w == 0.0f) { x = -30000.0f; y = -30000.0f; z = -30000.0f; }
        uint2 pk;
        pk.x = (unsigned)f2bf(x) | ((unsigned)f2bf(y) << 16);
        pk.y = (unsigned)f2bf(z);
        jT[aa*129 + rl] = pk;
    }
    __syncthreads();

    const int rl0 = w*32 + mlane, rl1 = rl0 + 16;
    const int r0 = bx*128 + rl0, r1 = r0 + 16;
    const int i0 = r0 / TOPK, i1 = r1 / TOPK;
    const int il0 = (i0 - i_base)*26, il1 = (i1 - i_base)*26;

    const float CC = fexp2(-2.0f * MUS2_C);

    f32x4 acc0[8], acc1[8];
    #pragma unroll
    for (int nt = 0; nt < 8; nt++) {
        acc0[nt] = (f32x4){0.f,0.f,0.f,0.f};
        acc1[nt] = (f32x4){0.f,0.f,0.f,0.f};
    }

    // K partition over 85 blocks: d0 = {0,11,22,33,44,55,65,75},
    // main iters ni = {11,11,11,11,11,10,10,9}; q==7 adds tail d=84.
    const int d0    = (q < 5) ? q*11 : (55 + (q-5)*10);
    const int nmain = (q < 5) ? 11 : ((q == 7) ? 9 : 10);

    // slot state: s = d*8 + 2*qd = a*26 + rem
    int s0i = d0*8 + 2*qd;
    int a = s0i / 26, rem = s0i - a*26;

    const char* Wb = (const char*)(ws + OFF_WSWZ) + (size_t)d0*16384 + (size_t)lane*32;

    for (int dd = 0; dd < nmain; dd++) {
        i32x8 b0 = *(const i32x8*)(Wb);
        i32x8 b1 = *(const i32x8*)(Wb + 2048);
        i32x8 b2 = *(const i32x8*)(Wb + 4096);
        i32x8 b3 = *(const i32x8*)(Wb + 6144);

        int rem1 = rem + 1, a1 = a;
        if (rem1 == 26) { rem1 = 0; a1 = a + 1; }

        uint2 jR0a = jT[rem*129  + rl0], jR0b = jT[rem1*129 + rl0];
        uint2 jR1a = jT[rem*129  + rl1], jR1b = jT[rem1*129 + rl1];
        float4 xiR0a = iT[il0 + a], xiR0b = iT[il0 + a1];
        float4 xiR1a = iT[il1 + a], xiR1b = iT[il1 + a1];

        uint4 p0a = gen16(xiR0a, bflo(jR0a.x), bfhi(jR0a.x), bflo(jR0a.y), CC);
        uint4 p0b = gen16(xiR0b, bflo(jR0b.x), bfhi(jR0b.x), bflo(jR0b.y), CC);
        uint4 p1a = gen16(xiR1a, bflo(jR1a.x), bfhi(jR1a.x), bflo(jR1a.y), CC);
        uint4 p1b = gen16(xiR1b, bflo(jR1b.x), bfhi(jR1b.x), bflo(jR1b.y), CC);

        i32x8 A0, A1;
        A0[0]=p0a.x; A0[1]=p0a.y; A0[2]=p0a.z; A0[3]=p0a.w;
        A0[4]=p0b.x; A0[5]=p0b.y; A0[6]=p0b.z; A0[7]=p0b.w;
        A1[0]=p1a.x; A1[1]=p1a.y; A1[2]=p1a.z; A1[3]=p1a.w;
        A1[4]=p1b.x; A1[5]=p1b.y; A1[6]=p1b.z; A1[7]=p1b.w;

        acc0[0] = __builtin_amdgcn_mfma_scale_f32_16x16x128_f8f6f4(A0, b0, acc0[0], 0, 0, 0, SCL1, 0, SCL1);
        acc1[0] = __builtin_amdgcn_mfma_scale_f32_16x16x128_f8f6f4(A1, b0, acc1[0], 0, 0, 0, SCL1, 0, SCL1);
        acc0[1] = __builtin_amdgcn_mfma_scale_f32_16x16x128_f8f6f4(A0, b1, acc0[1], 0, 0, 0, SCL1, 0, SCL1);
        acc1[1] = __builtin_amdgcn_mfma_scale_f32_16x16x128_f8f6f4(A1, b1, acc1[1], 0, 0, 0, SCL1, 0, SCL1);
        acc0[2] = __builtin_amdgcn_mfma_scale_f32_16x16x128_f8f6f4(A0, b2, acc0[2], 0, 0, 0, SCL1, 0, SCL1);
        acc1[2] = __builtin_amdgcn_mfma_scale_f32_16x16x128_f8f6f4(A1, b2, acc1[2], 0, 0, 0, SCL1, 0, SCL1);
        acc0[3] = __builtin_amdgcn_mfma_scale_f32_16x16x128_f8f6f4(A0, b3, acc0[3], 0, 0, 0, SCL1, 0, SCL1);
        acc1[3] = __builtin_amdgcn_mfma_scale_f32_16x16x128_f8f6f4(A1, b3, acc1[3], 0, 0, 0, SCL1, 0, SCL1);

        i32x8 b4 = *(const i32x8*)(Wb + 8192);
        i32x8 b5 = *(const i32x8*)(Wb + 10240);
        i32x8 b6 = *(const i32x8*)(Wb + 12288);
        i32x8 b7 = *(const i32x8*)(Wb + 14336);

        acc0[4] = __builtin_amdgcn_mfma_scale_f32_16x16x128_f8f6f4(A0, b4, acc0[4], 0, 0, 0, SCL1, 0, SCL1);
        acc1[4] = __builtin_amdgcn_mfma_scale_f32_16x16x128_f8f6f4(A1, b4, acc1[4], 0, 0, 0, SCL1, 0, SCL1);
        acc0[5] = __builtin_amdgcn_mfma_scale_f32_16x16x128_f8f6f4(A0, b5, acc0[5], 0, 0, 0, SCL1, 0, SCL1);
        acc1[5] = __builtin_amdgcn_mfma_scale_f32_16x16x128_f8f6f4(A1, b5, acc1[5], 0, 0, 0, SCL1, 0, SCL1);
        acc0[6] = __builtin_amdgcn_mfma_scale_f32_16x16x128_f8f6f4(A0, b6, acc0[6], 0, 0, 0, SCL1, 0, SCL1);
        acc1[6] = __builtin_amdgcn_mfma_scale_f32_16x16x128_f8f6f4(A1, b6, acc1[6], 0, 0, 0, SCL1, 0, SCL1);
        acc0[7] = __builtin_amdgcn_mfma_scale_f32_16x16x128_f8f6f4(A0, b7, acc0[7], 0, 0, 0, SCL1, 0, SCL1);
        acc1[7] = __builtin_amdgcn_mfma_scale_f32_16x16x128_f8f6f4(A1, b7, acc1[7], 0, 0, 0, SCL1, 0, SCL1);

        Wb += 16384;
        rem += 8;
        if (rem >= 26) { rem -= 26; a += 1; }
    }

    if (q == 7) {
        // tail d=84: qd0 slots 672/673, qd1 674/675 (RBF); qd2 676(pos)/677(0);
        // qd3 678/679 (0). State (a,rem) points at d=84; clamp a for safe reads.
        i32x8 b0 = *(const i32x8*)(Wb);
        i32x8 b1 = *(const i32x8*)(Wb + 2048);
        i32x8 b2 = *(const i32x8*)(Wb + 4096);
        i32x8 b3 = *(const i32x8*)(Wb + 6144);

        int rem1 = rem + 1, a1 = a;
        if (rem1 == 26) { rem1 = 0; a1 = a + 1; }
        int ac  = a  > 25 ? 25 : a;
        int a1c = a1 > 25 ? 25 : a1;

        uint2 jR0a = jT[rem*129  + rl0], jR0b = jT[rem1*129 + rl0];
        uint2 jR1a = jT[rem*129  + rl1], jR1b = jT[rem1*129 + rl1];
        float4 xiR0a = iT[il0 + ac], xiR0b = iT[il0 + a1c];
        float4 xiR1a = iT[il1 + ac], xiR1b = iT[il1 + a1c];

        uint4 p0a = gen16(xiR0a, bflo(jR0a.x), bfhi(jR0a.x), bflo(jR0a.y), CC);
        uint4 p0b = gen16(xiR0b, bflo(jR0b.x), bfhi(jR0b.x), bflo(jR0b.y), CC);
        uint4 p1a = gen16(xiR1a, bflo(jR1a.x), bfhi(jR1a.x), bflo(jR1a.y), CC);
        uint4 p1b = gen16(xiR1b, bflo(jR1b.x), bfhi(jR1b.x), bflo(jR1b.y), CC);

        if (qd == 2) {   // slot 676 = positional; 677 = zero
            int dc0, dc1;
            {
                int j0 = JrowS[rl0], j1 = JrowS[rl1];
                int off  = Ridx[i0] - Ridx[j0];
                int same = (chain[i0] == chain[j0]);
                int dc = off + 32; dc = dc < 0 ? 0 : (dc > 64 ? 64 : dc);
                dc0 = same ? dc : 65;
                off  = Ridx[i1] - Ridx[j1];
                same = (chain[i1] == chain[j1]);
                dc = off + 32; dc = dc < 0 ? 0 : (dc > 64 ? 64 : dc);
                dc1 = same ? dc : 65;
            }
            float e0[16], e1[16];
            #pragma unroll
            for (int f = 0; f < 16; f++) {
                float bv = bp[f];
                e0[f] = Wp[f*66 + dc0] + bv;
                e1[f] = Wp[f*66 + dc1] + bv;
            }
            int u0 = __builtin_amdgcn_cvt_pk_fp8_f32(e0[0], e0[1], 0, false);
            u0     = __builtin_amdgcn_cvt_pk_fp8_f32(e0[2], e0[3], u0, true);
            int u1 = __builtin_amdgcn_cvt_pk_fp8_f32(e0[4], e0[5], 0, false);
            u1     = __builtin_amdgcn_cvt_pk_fp8_f32(e0[6], e0[7], u1, true);
            int u2 = __builtin_amdgcn_cvt_pk_fp8_f32(e0[8], e0[9], 0, false);
            u2     = __builtin_amdgcn_cvt_pk_fp8_f32(e0[10], e0[11], u2, true);
            int u3 = __builtin_amdgcn_cvt_pk_fp8_f32(e0[12], e0[13], 0, false);
            u3     = __builtin_amdgcn_cvt_pk_fp8_f32(e0[14], e0[15], u3, true);
            p0a = make_uint4((unsigned)u0,(unsigned)u1,(unsigned)u2,(unsigned)u3);
            u0 = __builtin_amdgcn_cvt_pk_fp8_f32(e1[0], e1[1], 0, false);
            u0 = __builtin_amdgcn_cvt_pk_fp8_f32(e1[2], e1[3], u0, true);
            u1 = __builtin_amdgcn_cvt_pk_fp8_f32(e1[4], e1[5], 0, false);
            u1 = __builtin_amdgcn_cvt_pk_fp8_f32(e1[6], e1[7], u1, true);
            u2 = __builtin_amdgcn_cvt_pk_fp8_f32(e1[8], e1[9], 0, false);
            u2 = __builtin_amdgcn_cvt_pk_fp8_f32(e1[10], e1[11], u2, true);
            u3 = __builtin_amdgcn_cvt_pk_fp8_f32(e1[12], e1[13], 0, false);
            u3 = __builtin_amdgcn_cvt_pk_fp8_f32(e1[14], e1[15], u3, true);
            p1a = make_uint4((unsigned)u0,(unsigned)u1,(unsigned)u2,(unsigned)u3);
            p0b = make_uint4(0,0,0,0);
            p1b = make_uint4(0,0,0,0);
        }
        if (qd == 3) {
            p0a = make_uint4(0,0,0,0); p0b = make_uint4(0,0,0,0);
            p1a = make_uint4(0,0,0,0); p1b = make_uint4(0,0,0,0);
        }

        i32x8 A0, A1;
        A0[0]=p0a.x; A0[1]=p0a.y; A0[2]=p0a.z; A0[3]=p0a.w;
        A0[4]=p0b.x; A0[5]=p0b.y; A0[6]=p0b.z; A0[7]=p0b.w;
        A1[0]=p1a.x; A1[1]=p1a.y; A1[2]=p1a.z; A1[3]=p1a.w;
        A1[4]=p1b.x; A1[5]=p1b.y; A1[6]=p1b.z; A1[7]=p1b.w;

        acc0[0] = __builtin_amdgcn_mfma_scale_f32_16x16x128_f8f6f4(A0, b0, acc0[0], 0, 0, 0, SCL1, 0, SCL1);
        acc1[0] = __builtin_amdgcn_mfma_scale_f32_16x16x128_f8f6f4(A1, b0, acc1[0], 0, 0, 0, SCL1, 0, SCL1);
        acc0[1] = __builtin_amdgcn_mfma_scale_f32_16x16x128_f8f6f4(A0, b1, acc0[1], 0, 0, 0, SCL1, 0, SCL1);
        acc1[1] = __builtin_amdgcn_mfma_scale_f32_16x16x128_f8f6f4(A1, b1, acc1[1], 0, 0, 0, SCL1, 0, SCL1);
        acc0[2] = __builtin_amdgcn_mfma_scale_f32_16x16x128_f8f6f4(A0, b2, acc0[2], 0, 0, 0, SCL1, 0, SCL1);
        acc1[2] = __builtin_amdgcn_mfma_scale_f32_16x16x128_f8f6f4(A1, b2, acc1[2], 0, 0, 0, SCL1, 0, SCL1);
        acc0[3] = __builtin_amdgcn_mfma_scale_f32_16x16x128_f8f6f4(A0, b3, acc0[3], 0, 0, 0, SCL1, 0, SCL1);
        acc1[3] = __builtin_amdgcn_mfma_scale_f32_16x16x128_f8f6f4(A1, b3, acc1[3], 0, 0, 0, SCL1, 0, SCL1);

        i32x8 b4 = *(const i32x8*)(Wb + 8192);
        i32x8 b5 = *(const i32x8*)(Wb + 10240);
        i32x8 b6 = *(const i32x8*)(Wb + 12288);
        i32x8 b7 = *(const i32x8*)(Wb + 14336);

        acc0[4] = __builtin_amdgcn_mfma_scale_f32_16x16x128_f8f6f4(A0, b4, acc0[4], 0, 0, 0, SCL1, 0, SCL1);
        acc1[4] = __builtin_amdgcn_mfma_scale_f32_16x16x128_f8f6f4(A1, b4, acc1[4], 0, 0, 0, SCL1, 0, SCL1);
        acc0[5] = __builtin_amdgcn_mfma_scale_f32_16x16x128_f8f6f4(A0, b5, acc0[5], 0, 0, 0, SCL1, 0, SCL1);
        acc1[5] = __builtin_amdgcn_mfma_scale_f32_16x16x128_f8f6f4(A1, b5, acc1[5], 0, 0, 0, SCL1, 0, SCL1);
        acc0[6] = __builtin_amdgcn_mfma_scale_f32_16x16x128_f8f6f4(A0, b6, acc0[6], 0, 0, 0, SCL1, 0, SCL1);
        acc1[6] = __builtin_amdgcn_mfma_scale_f32_16x16x128_f8f6f4(A1, b6, acc1[6], 0, 0, 0, SCL1, 0, SCL1);
        acc0[7] = __builtin_amdgcn_mfma_scale_f32_16x16x128_f8f6f4(A0, b7, acc0[7], 0, 0, 0, SCL1, 0, SCL1);
        acc1[7] = __builtin_amdgcn_mfma_scale_f32_16x16x128_f8f6f4(A1, b7, acc1[7], 0, 0, 0, SCL1, 0, SCL1);
    }

    // epilogue: bf16 partials. D layout: col = lane&15, row = qd*4 + rr.
    #pragma unroll
    for (int nt = 0; nt < 8; nt++) {
        int col = nt*16 + mlane;
        #pragma unroll
        for (int rr = 0; rr < 4; rr++) {
            int g0 = bx*128 + w*32 + qd*4 + rr;
            Ep[(size_t)g0*NOUT + col]      = f2bf(acc0[nt][rr]);
            Ep[(size_t)(g0+16)*NOUT + col] = f2bf(acc1[nt][rr]);
        }
    }
}

// ---------------------------------------------------------------- kernel D --
// Wave per row: 64 lanes x 2 cols (uint bf16-pair loads), shuffle-only LN.
__global__ __launch_bounds__(256) void kD(const float* __restrict__ ge,
                                          const float* __restrict__ be,
                                          char* __restrict__ ws,
                                          float* __restrict__ out)
{
    const unsigned* Ep = (const unsigned*)(ws + OFF_EPART);
    const int t = threadIdx.x, wv = t >> 6, lane = t & 63;
    const int row = blockIdx.x*4 + wv;
    const size_t qs = (size_t)MTOT * 64;           // uints per partial set
    size_t b = (size_t)row*64 + lane;

    float v0 = 0.f, v1 = 0.f;
    #pragma unroll
    for (int qq = 0; qq < KSPLIT; qq++) {
        unsigned u = Ep[b + (size_t)qq*qs];
        v0 += bf2f((unsigned short)(u & 0xffffu));
        v1 += bf2f((unsigned short)(u >> 16));
    }

    float S = v0 + v1, Q = v0*v0 + v1*v1;
    #pragma unroll
    for (int off = 32; off; off >>= 1) {
        S += __shfl_xor(S, off, 64);
        Q += __shfl_xor(Q, off, 64);
    }
    float mean = S * (1.0f/128.0f);
    float var  = Q * (1.0f/128.0f) - mean*mean;
    float rstd = rsqrtf(var + 1e-5f);
    float2 o;
    o.x = (v0 - mean) * rstd * ge[2*lane]   + be[2*lane];
    o.y = (v1 - mean) * rstd * ge[2*lane+1] + be[2*lane+1];
    ((float2*)(out + OUT_E))[(size_t)row*64 + lane] = o;
}

// ------------------------------------------------------------------- launch --
extern "C" void kernel_launch(void* const* d_in, const int* in_sizes, int n_in,
                              void* d_out, int out_size, void* d_ws, size_t ws_size,
                              hipStream_t stream)
{
    const float* X     = (const float*)d_in[0];
    const int*   Ridx  = (const int*)d_in[2];
    const int*   chain = (const int*)d_in[3];
    const float* Xm    = (const float*)d_in[4];
    const float* prot  = (const float*)d_in[5];
    const float* dna   = (const float*)d_in[6];
    const float* rna   = (const float*)d_in[7];
    const int*   ptype = (const int*)d_in[8];
    const float* Wp    = (const float*)d_in[9];
    const float* bp    = (const float*)d_in[10];
    const float* We    = (const float*)d_in[11];
    const float* Wn    = (const float*)d_in[12];
    const float* ge    = (const float*)d_in[13];
    const float* be    = (const float*)d_in[14];
    const float* gn    = (const float*)d_in[15];
    const float* bn    = (const float*)d_in[16];
    char* ws = (char*)d_ws;
    float* out = (float*)d_out;

    kPrep<<<dim3(NRES + 384), dim3(256), 0, stream>>>(X, Xm, prot, dna, rna,
            ptype, Wn, gn, bn, We, ws, out);
    kC<<<dim3(120, KSPLIT), dim3(256), 0, stream>>>(Ridx, chain, Wp, bp, ws);
    kD<<<dim3(MTOT/4), dim3(256), 0, stream>>>(ge, be, ws, out);
}